// Round 1
// baseline (11.742 us; speedup 1.0000x reference)
//
#include <hip/hip_runtime.h>

// DigitCapsules: routing collapses analytically (u_hat constant over capsule
// axis -> softmax stays uniform -> v[b,i,:] = squash(mean_r u_core[b,r,:])).
//
// x: [32, 8, 24, 24] fp32, W: [32, 576, 8, 16] fp32, out: [32, 576, 16] fp32.

#define NB 32
#define NR 576
#define NC 8
#define ND 16
#define NBLK 9   // partial-reduction blocks per batch element (64 r's each)

__global__ __launch_bounds__(64) void caps_partial(const float* __restrict__ x,
                                                   const float* __restrict__ W,
                                                   float* __restrict__ partial) {
    const int b    = blockIdx.x;
    const int blk  = blockIdx.y;
    const int lane = threadIdx.x;            // 0..63
    const int r    = blk * 64 + lane;        // < 576 always (9*64 = 576)

    const float* xb = x + (size_t)b * NC * NR;
    const float* Wr = W + ((size_t)b * NR + r) * NC * ND;

    // x2[b, r, k] = x[b, k, r]  (coalesced across lanes per k)
    float xv[NC];
#pragma unroll
    for (int k = 0; k < NC; ++k) xv[k] = xb[k * NR + r];

    float acc[ND];
#pragma unroll
    for (int j = 0; j < ND; ++j) acc[j] = 0.f;

    // u_core[b,r,j] = sum_k x2[b,r,k] * W[b,r,k,j]
#pragma unroll
    for (int k = 0; k < NC; ++k) {
        const float4 w0 = *reinterpret_cast<const float4*>(Wr + k * ND + 0);
        const float4 w1 = *reinterpret_cast<const float4*>(Wr + k * ND + 4);
        const float4 w2 = *reinterpret_cast<const float4*>(Wr + k * ND + 8);
        const float4 w3 = *reinterpret_cast<const float4*>(Wr + k * ND + 12);
        const float xk = xv[k];
        acc[0]  += xk * w0.x;  acc[1]  += xk * w0.y;
        acc[2]  += xk * w0.z;  acc[3]  += xk * w0.w;
        acc[4]  += xk * w1.x;  acc[5]  += xk * w1.y;
        acc[6]  += xk * w1.z;  acc[7]  += xk * w1.w;
        acc[8]  += xk * w2.x;  acc[9]  += xk * w2.y;
        acc[10] += xk * w2.z;  acc[11] += xk * w2.w;
        acc[12] += xk * w3.x;  acc[13] += xk * w3.y;
        acc[14] += xk * w3.z;  acc[15] += xk * w3.w;
    }

    // butterfly reduce the 16-vector across the 64-lane wave
#pragma unroll
    for (int j = 0; j < ND; ++j) {
        for (int m = 1; m < 64; m <<= 1)
            acc[j] += __shfl_xor(acc[j], m, 64);
    }

    if (lane == 0) {
        float* p = partial + ((size_t)b * NBLK + blk) * ND;
#pragma unroll
        for (int j = 0; j < ND; ++j) p[j] = acc[j];
    }
}

__global__ __launch_bounds__(256) void caps_finish(const float* __restrict__ partial,
                                                   float* __restrict__ out) {
    const int b   = blockIdx.x;
    const int tid = threadIdx.x;

    // every thread redundantly sums the 9 partial 16-vectors (L2-broadcast, cheap)
    float s[ND];
#pragma unroll
    for (int j = 0; j < ND; ++j) s[j] = 0.f;
    const float* p = partial + (size_t)b * NBLK * ND;
    for (int q = 0; q < NBLK; ++q) {
#pragma unroll
        for (int j = 0; j < ND; ++j) s[j] += p[q * ND + j];
    }

    const float cmean = 1.0f / 576.0f;   // uniform softmax coefficient
    float norm = 0.f;
#pragma unroll
    for (int j = 0; j < ND; ++j) { s[j] *= cmean; norm += s[j] * s[j]; }

    // squash: (norm/(1+norm)) * s / sqrt(norm + 1e-8)
    const float sc = norm / ((1.0f + norm) * sqrtf(norm + 1e-8f));

    float v[ND];
#pragma unroll
    for (int j = 0; j < ND; ++j) v[j] = s[j] * sc;

    const float4 q0 = make_float4(v[0],  v[1],  v[2],  v[3]);
    const float4 q1 = make_float4(v[4],  v[5],  v[6],  v[7]);
    const float4 q2 = make_float4(v[8],  v[9],  v[10], v[11]);
    const float4 q3 = make_float4(v[12], v[13], v[14], v[15]);

    const int qi = tid & 3;
    const float4 vq = (qi == 0) ? q0 : (qi == 1) ? q1 : (qi == 2) ? q2 : q3;

    // broadcast write out[b, i, j] = v[j]: 576*16 floats = 2304 float4 per b.
    // thread writes indices tid + 256*s; (tid + 256*s) % 4 == tid % 4.
    float4* ob = reinterpret_cast<float4*>(out + (size_t)b * NR * ND);
#pragma unroll
    for (int sdx = 0; sdx < 9; ++sdx) ob[tid + 256 * sdx] = vq;
}

extern "C" void kernel_launch(void* const* d_in, const int* in_sizes, int n_in,
                              void* d_out, int out_size, void* d_ws, size_t ws_size,
                              hipStream_t stream) {
    const float* x = (const float*)d_in[0];       // [32, 8, 24, 24]
    const float* W = (const float*)d_in[1];       // [32, 576, 8, 16]
    float* out     = (float*)d_out;               // [32, 576, 16]
    float* partial = (float*)d_ws;                // 32*9*16 floats = 18 KB

    dim3 gridA(NB, NBLK);
    caps_partial<<<gridA, 64, 0, stream>>>(x, W, partial);
    caps_finish<<<NB, 256, 0, stream>>>(partial, out);
}